// Round 1
// baseline (795.209 us; speedup 1.0000x reference)
//
#include <hip/hip_runtime.h>

#define NNETS 10
#define BATCH 8192

// fast tanh: 1 - 2/(1+e^{2x}); saturates correctly for |x| large (exp -> inf/0)
__device__ __forceinline__ float fast_tanh(float x) {
    float e = __expf(2.f * x);
    return 1.f - 2.f / (1.f + e);
}

// Middle layer: in LDS bufIn[ID][65] -> out LDS bufOut[OD][65].
// Wave w computes outputs [w*NO, w*NO+NO) (guarded for OD=3 case).
// Weight addresses are lane-invariant -> scalar loads expected.
template<int ID, int OD, int NO, bool RELU>
__device__ __forceinline__ void midlayer(const float* __restrict__ W,
                                         const float* __restrict__ bias,
                                         const float* bufIn, float* bufOut,
                                         int n, int w, int lane) {
    const int o0 = w * NO;
    if (o0 < OD) {
        float acc[NO];
#pragma unroll
        for (int j = 0; j < NO; ++j) acc[j] = bias[n * OD + o0 + j];
        for (int k = 0; k < ID; ++k) {
            float a = bufIn[k * 65 + lane];
            const float* Wk = W + ((size_t)n * ID + k) * OD + o0;
#pragma unroll
            for (int j = 0; j < NO; ++j) acc[j] = fmaf(a, Wk[j], acc[j]);
        }
#pragma unroll
        for (int j = 0; j < NO; ++j) {
            float v = acc[j];
            if (RELU) v = fmaxf(v, 0.f);
            bufOut[(o0 + j) * 65 + lane] = v;
        }
    }
    __syncthreads();
}

__global__ __launch_bounds__(256)
void fused_ae_kernel(const float* __restrict__ x,
                     const float* __restrict__ W0, const float* __restrict__ B0,
                     const float* __restrict__ W1, const float* __restrict__ B1,
                     const float* __restrict__ W2, const float* __restrict__ B2,
                     const float* __restrict__ W3, const float* __restrict__ B3,
                     const float* __restrict__ W4, const float* __restrict__ B4,
                     const float* __restrict__ W5, const float* __restrict__ B5,
                     const float* __restrict__ W6, const float* __restrict__ B6,
                     const float* __restrict__ W7, const float* __restrict__ B7,
                     float* __restrict__ out) {
    __shared__ float HsA[128 * 65];   // 33.3 KB: h0 / h2 / h4 / h6
    __shared__ float HsB[64 * 65];    // 16.6 KB: x-stage / h1 / h3 / h5 / partials

    const int t    = threadIdx.x;
    const int lane = t & 63;
    const int w    = __builtin_amdgcn_readfirstlane(t >> 6);  // wave id 0..3
    const int n    = blockIdx.x;                              // net 0..9
    const int rowbase = blockIdx.y * 64;                      // batch rows

    // ---------------- Layer 0: x[64][784] @ W0[n][784][128], relu ----------------
    // wave w owns output cols [w*32, w*32+32); lane = row.
    float acc0[32];
#pragma unroll
    for (int j = 0; j < 32; ++j) acc0[j] = 0.f;

    float* As = HsB;                  // x-stage buffer As[16][65], overlaid on HsB
    const int r   = t >> 2;           // row staged by this thread (0..63)
    const int kk4 = (t & 3) * 4;      // k offset within chunk
    const float* xrow = x + (size_t)(rowbase + r) * 784;

    for (int kc = 0; kc < 49; ++kc) {
        // cooperative stage: 64 rows x 16 k, transposed As[k][row]
        float4 xv = *(const float4*)(xrow + kc * 16 + kk4);
        As[(kk4 + 0) * 65 + r] = xv.x;
        As[(kk4 + 1) * 65 + r] = xv.y;
        As[(kk4 + 2) * 65 + r] = xv.z;
        As[(kk4 + 3) * 65 + r] = xv.w;
        __syncthreads();
        const float* W0base = W0 + ((size_t)n * 784 + (size_t)kc * 16) * 128 + w * 32;
#pragma unroll
        for (int k = 0; k < 16; ++k) {
            float a = As[k * 65 + lane];
            const float* Wk = W0base + k * 128;
#pragma unroll
            for (int j = 0; j < 32; ++j) acc0[j] = fmaf(a, Wk[j], acc0[j]);
        }
        __syncthreads();  // before next stage overwrites As
    }
    {
        const float* bb = B0 + n * 128 + w * 32;
#pragma unroll
        for (int j = 0; j < 32; ++j) {
            float v = fmaxf(acc0[j] + bb[j], 0.f);
            HsA[(w * 32 + j) * 65 + lane] = v;
        }
    }
    __syncthreads();

    // ---------------- Layers 1..6 (LDS ping-pong) ----------------
    midlayer<128, 64, 16, true >(W1, B1, HsA, HsB, n, w, lane);  // h0(A)->h1(B)
    midlayer< 64, 12,  3, true >(W2, B2, HsB, HsA, n, w, lane);  // h1(B)->h2(A)
    midlayer< 12,  3,  1, false>(W3, B3, HsA, HsB, n, w, lane);  // h2(A)->h3(B)  latent, no act
    midlayer<  3, 12,  3, true >(W4, B4, HsB, HsA, n, w, lane);  // h3(B)->h4(A)
    midlayer< 12, 64, 16, true >(W5, B5, HsA, HsB, n, w, lane);  // h4(A)->h5(B)
    midlayer< 64,128, 32, true >(W6, B6, HsB, HsA, n, w, lane);  // h5(B)->h6(A)

    // ---------------- Layer 7: h6[64][128] @ W7[n][128][784], tanh, row-sum ------
    // wave w owns cols [w*196, w*196+196) in 7 chunks of 28.
    float lane_sum = 0.f;
    const int j0w = w * 196;
    for (int c = 0; c < 7; ++c) {
        const int j0 = j0w + c * 28;
        float acc[28];
        const float* bb = B7 + n * 784 + j0;
#pragma unroll
        for (int j = 0; j < 28; ++j) acc[j] = bb[j];
        for (int k = 0; k < 128; ++k) {
            float a = HsA[k * 65 + lane];
            const float* Wk = W7 + ((size_t)n * 128 + k) * 784 + j0;
#pragma unroll
            for (int j = 0; j < 28; ++j) acc[j] = fmaf(a, Wk[j], acc[j]);
        }
#pragma unroll
        for (int j = 0; j < 28; ++j) lane_sum += fast_tanh(acc[j]);
    }

    // reduce the 4 wave partials (HsB region is dead now)
    float* partial = HsB;
    partial[w * 64 + lane] = lane_sum;
    __syncthreads();
    if (t < 64) {
        float s = partial[t] + partial[64 + t] + partial[128 + t] + partial[192 + t];
        out[(size_t)(rowbase + t) * 10 + n] = s;
    }
}

extern "C" void kernel_launch(void* const* d_in, const int* in_sizes, int n_in,
                              void* d_out, int out_size, void* d_ws, size_t ws_size,
                              hipStream_t stream) {
    (void)in_sizes; (void)n_in; (void)out_size; (void)d_ws; (void)ws_size;
    const float* x  = (const float*)d_in[0];
    const float* W0 = (const float*)d_in[1];  const float* B0 = (const float*)d_in[2];
    const float* W1 = (const float*)d_in[3];  const float* B1 = (const float*)d_in[4];
    const float* W2 = (const float*)d_in[5];  const float* B2 = (const float*)d_in[6];
    const float* W3 = (const float*)d_in[7];  const float* B3 = (const float*)d_in[8];
    const float* W4 = (const float*)d_in[9];  const float* B4 = (const float*)d_in[10];
    const float* W5 = (const float*)d_in[11]; const float* B5 = (const float*)d_in[12];
    const float* W6 = (const float*)d_in[13]; const float* B6 = (const float*)d_in[14];
    const float* W7 = (const float*)d_in[15]; const float* B7 = (const float*)d_in[16];
    float* out = (float*)d_out;

    dim3 grid(NNETS, BATCH / 64, 1);
    dim3 block(256, 1, 1);
    hipLaunchKernelGGL(fused_ae_kernel, grid, block, 0, stream,
                       x, W0, B0, W1, B1, W2, B2, W3, B3,
                       W4, B4, W5, B5, W6, B6, W7, B7, out);
}

// Round 2
// 389.449 us; speedup vs baseline: 2.0419x; 2.0419x over previous
//
#include <hip/hip_runtime.h>

#define NNETS 10
#define BATCH 8192

typedef __attribute__((ext_vector_type(8)))  short  short8;
typedef __attribute__((ext_vector_type(16))) float  f32x16;

// ---------------- workspace layout (bytes) ----------------
// xpack : [rt(256)][kc(49)][hl(2)][lane(64)][j(8)] bf16   = 25,690,112 B
// w0pack: [n(10)][kc(49)][ct(4)][hl(2)][lane(64)][j(8)]   =  4,014,080 B
// w7pack: [n(10)][kc(8)][ct(25)][hl(2)][lane(64)][j(8)]   =  4,096,000 B
#define XPACK_BYTES  (256UL*49*2*64*8*2)
#define W0PACK_OFF   (XPACK_BYTES)
#define W0PACK_BYTES (10UL*49*4*2*64*8*2)
#define W7PACK_OFF   (W0PACK_OFF + W0PACK_BYTES)
#define W7PACK_BYTES (10UL*8*25*2*64*8*2)
#define TOTAL_WS     (W7PACK_OFF + W7PACK_BYTES)

// ---------------- helpers ----------------
__device__ __forceinline__ float fast_tanh(float x) {
    float e = __expf(2.f * x);
    return 1.f - 2.f / (1.f + e);
}
__device__ __forceinline__ unsigned short bf16_rne(float v) {
    unsigned u = __float_as_uint(v);
    unsigned r = (u + 0x7FFFu + ((u >> 16) & 1u)) >> 16;
    return (unsigned short)r;
}
__device__ __forceinline__ float bf16_to_f(unsigned short h) {
    return __uint_as_float(((unsigned)h) << 16);
}

// ---------------- pack kernels (run every launch; rewrite all ws they read) ----
__global__ __launch_bounds__(256)
void pack_x_kernel(const float* __restrict__ x, unsigned short* __restrict__ xp) {
    int tid = blockIdx.x * 256 + threadIdx.x;           // 256*49*64 = 802816
    if (tid >= 256 * 49 * 64) return;
    int lane = tid & 63; int t2 = tid >> 6;
    int kc = t2 % 49;    int rt = t2 / 49;
    int row = rt * 32 + (lane & 31);
    int kb  = kc * 16 + 8 * (lane >> 5);
    const float* src = x + (size_t)row * 784 + kb;
    short8 H, L;
#pragma unroll
    for (int j = 0; j < 8; ++j) {
        float v = src[j];
        unsigned short h = bf16_rne(v);
        H[j] = (short)h;
        L[j] = (short)bf16_rne(v - bf16_to_f(h));
    }
    short8* dst = reinterpret_cast<short8*>(xp + (size_t)(rt * 49 + kc) * 1024) + lane;
    dst[0]  = H;
    dst[64] = L;
}

__global__ __launch_bounds__(256)
void pack_w0_kernel(const float* __restrict__ W0, unsigned short* __restrict__ wp) {
    int tid = blockIdx.x * 256 + threadIdx.x;           // 10*49*4*64 = 125440
    if (tid >= 10 * 49 * 4 * 64) return;
    int lane = tid & 63; int t2 = tid >> 6;
    int ct = t2 % 4;  t2 /= 4;
    int kc = t2 % 49; int n = t2 / 49;
    int col = ct * 32 + (lane & 31);
    int kb  = kc * 16 + 8 * (lane >> 5);
    short8 H, L;
#pragma unroll
    for (int j = 0; j < 8; ++j) {
        float v = W0[((size_t)n * 784 + kb + j) * 128 + col];
        unsigned short h = bf16_rne(v);
        H[j] = (short)h;
        L[j] = (short)bf16_rne(v - bf16_to_f(h));
    }
    short8* dst = reinterpret_cast<short8*>(wp + (size_t)((n * 49 + kc) * 4 + ct) * 1024) + lane;
    dst[0]  = H;
    dst[64] = L;
}

__global__ __launch_bounds__(256)
void pack_w7_kernel(const float* __restrict__ W7, unsigned short* __restrict__ wp) {
    int tid = blockIdx.x * 256 + threadIdx.x;           // 10*8*25*64 = 128000
    if (tid >= 10 * 8 * 25 * 64) return;
    int lane = tid & 63; int t2 = tid >> 6;
    int ct = t2 % 25; t2 /= 25;
    int kc = t2 % 8;  int n = t2 / 8;
    int col = ct * 32 + (lane & 31);
    int kb  = kc * 16 + 8 * (lane >> 5);
    short8 H, L;
#pragma unroll
    for (int j = 0; j < 8; ++j) {
        float v = (col < 784) ? W7[((size_t)n * 128 + kb + j) * 784 + col] : 0.f;
        unsigned short h = bf16_rne(v);
        H[j] = (short)h;
        L[j] = (short)bf16_rne(v - bf16_to_f(h));
    }
    short8* dst = reinterpret_cast<short8*>(wp + (size_t)((n * 8 + kc) * 25 + ct) * 1024) + lane;
    dst[0]  = H;
    dst[64] = L;
}

// ---------------- mid layers (fp32 VALU, as round 1) ----------------
template<int ID, int OD, int NO, bool RELU>
__device__ __forceinline__ void midlayer(const float* __restrict__ W,
                                         const float* __restrict__ bias,
                                         const float* bufIn, float* bufOut,
                                         int n, int w, int lane) {
    const int o0 = w * NO;
    if (o0 < OD) {
        float acc[NO];
#pragma unroll
        for (int j = 0; j < NO; ++j) acc[j] = bias[n * OD + o0 + j];
        for (int k = 0; k < ID; ++k) {
            float a = bufIn[k * 65 + lane];
            const float* Wk = W + ((size_t)n * ID + k) * OD + o0;
#pragma unroll
            for (int j = 0; j < NO; ++j) acc[j] = fmaf(a, Wk[j], acc[j]);
        }
#pragma unroll
        for (int j = 0; j < NO; ++j) {
            float v = acc[j];
            if (RELU) v = fmaxf(v, 0.f);
            bufOut[(o0 + j) * 65 + lane] = v;
        }
    }
    __syncthreads();
}

#define MFMA32(A, B, C) __builtin_amdgcn_mfma_f32_32x32x16_bf16(A, B, C, 0, 0, 0)

// ---------------- main fused kernel (MFMA L0/L7) ----------------
__global__ __launch_bounds__(256)
void fused_ae_mfma_kernel(const float* __restrict__ x,
                          const float* __restrict__ B0,
                          const float* __restrict__ W1, const float* __restrict__ B1,
                          const float* __restrict__ W2, const float* __restrict__ B2,
                          const float* __restrict__ W3, const float* __restrict__ B3,
                          const float* __restrict__ W4, const float* __restrict__ B4,
                          const float* __restrict__ W5, const float* __restrict__ B5,
                          const float* __restrict__ W6, const float* __restrict__ B6,
                          const float* __restrict__ B7,
                          const unsigned short* __restrict__ ws_u16,
                          float* __restrict__ out) {
    __shared__ float HsA[128 * 65];   // 33.3 KB
    __shared__ float HsB[64 * 65];    // 16.6 KB

    const int t    = threadIdx.x;
    const int lane = t & 63;
    const int w    = __builtin_amdgcn_readfirstlane(t >> 6);  // wave 0..3
    const int n    = blockIdx.x;
    const int cl   = lane & 31;       // col-within-tile / row-within-tile
    const int hf   = lane >> 5;
    const int rtl  = w >> 1;          // local row-tile 0/1 (32 rows each)
    const int ct0  = (w & 1) * 2;     // L0 col-tiles {0,1} or {2,3}

    const short8* xp8  = reinterpret_cast<const short8*>(ws_u16);
    const short8* w0p8 = reinterpret_cast<const short8*>(ws_u16 + W0PACK_OFF / 2);
    const short8* w7p8 = reinterpret_cast<const short8*>(ws_u16 + W7PACK_OFF / 2);

    // ================= Layer 0: x @ W0 -> h0[128][64], relu =================
    const int rt = blockIdx.y * 2 + rtl;                  // global 32-row tile
    f32x16 acc0, acc1;
#pragma unroll
    for (int i = 0; i < 16; ++i) { acc0[i] = 0.f; acc1[i] = 0.f; }

    const short8* xA = xp8 + (size_t)rt * 49 * 128 + lane;              // kc stride 128
    const short8* wB = w0p8 + ((size_t)n * 49 * 4 + ct0) * 128 + lane;  // kc stride 512

    short8 Ah = xA[0], Al = xA[64];
    short8 Bh0 = wB[0], Bl0 = wB[64], Bh1 = wB[128], Bl1 = wB[192];
    for (int kc = 0; kc < 49; ++kc) {
        short8 nAh, nAl, nBh0, nBl0, nBh1, nBl1;
        if (kc < 48) {
            const short8* xn = xA + (size_t)(kc + 1) * 128;
            const short8* wn = wB + (size_t)(kc + 1) * 512;
            nAh = xn[0]; nAl = xn[64];
            nBh0 = wn[0]; nBl0 = wn[64]; nBh1 = wn[128]; nBl1 = wn[192];
        }
        acc0 = MFMA32(Ah, Bh0, acc0);
        acc0 = MFMA32(Ah, Bl0, acc0);
        acc0 = MFMA32(Al, Bh0, acc0);
        acc1 = MFMA32(Ah, Bh1, acc1);
        acc1 = MFMA32(Ah, Bl1, acc1);
        acc1 = MFMA32(Al, Bh1, acc1);
        if (kc < 48) { Ah = nAh; Al = nAl; Bh0 = nBh0; Bl0 = nBl0; Bh1 = nBh1; Bl1 = nBl1; }
    }
    {
        float b0a = B0[n * 128 + ct0 * 32 + cl];
        float b0b = B0[n * 128 + (ct0 + 1) * 32 + cl];
#pragma unroll
        for (int r2 = 0; r2 < 16; ++r2) {
            int row = rtl * 32 + (r2 & 3) + 8 * (r2 >> 2) + 4 * hf;
            HsA[(ct0 * 32 + cl) * 65 + row]       = fmaxf(acc0[r2] + b0a, 0.f);
            HsA[((ct0 + 1) * 32 + cl) * 65 + row] = fmaxf(acc1[r2] + b0b, 0.f);
        }
    }
    __syncthreads();

    // ================= Layers 1..6 (fp32 VALU, LDS ping-pong) ================
    midlayer<128, 64, 16, true >(W1, B1, HsA, HsB, n, w, lane);
    midlayer< 64, 12,  3, true >(W2, B2, HsB, HsA, n, w, lane);
    midlayer< 12,  3,  1, false>(W3, B3, HsA, HsB, n, w, lane);
    midlayer<  3, 12,  3, true >(W4, B4, HsB, HsA, n, w, lane);
    midlayer< 12, 64, 16, true >(W5, B5, HsA, HsB, n, w, lane);
    midlayer< 64,128, 32, true >(W6, B6, HsB, HsA, n, w, lane);
    // h6 now in HsA[feat 0..127][row 0..63]

    // ================= Layer 7: h6 @ W7, tanh, row-sum =======================
    // Build A fragments (hi/lo) for this wave's 32 rows, all 8 k-chunks.
    short8 a_hi[8], a_lo[8];
    {
        const int r32 = rtl * 32 + cl;   // this lane's block-local batch row
#pragma unroll
        for (int kc = 0; kc < 8; ++kc) {
            int kb = kc * 16 + 8 * hf;
            short8 H, L;
#pragma unroll
            for (int j = 0; j < 8; ++j) {
                float v = HsA[(kb + j) * 65 + r32];
                unsigned short h = bf16_rne(v);
                H[j] = (short)h;
                L[j] = (short)bf16_rne(v - bf16_to_f(h));
            }
            a_hi[kc] = H; a_lo[kc] = L;
        }
    }

    float rowsum[16];
#pragma unroll
    for (int i = 0; i < 16; ++i) rowsum[i] = 0.f;

    const short8* w7b = w7p8 + (size_t)n * 8 * 25 * 128 + lane;
    const int ctS = (w & 1) ? 13 : 0;
    const int ctE = (w & 1) ? 25 : 13;
    for (int ct = ctS; ct < ctE; ++ct) {
        f32x16 acc;
#pragma unroll
        for (int i = 0; i < 16; ++i) acc[i] = 0.f;
#pragma unroll
        for (int kc = 0; kc < 8; ++kc) {
            const short8* bp = w7b + (size_t)(kc * 25 + ct) * 128;
            short8 Bh = bp[0], Bl = bp[64];
            acc = MFMA32(a_hi[kc], Bh, acc);
            acc = MFMA32(a_hi[kc], Bl, acc);
            acc = MFMA32(a_lo[kc], Bh, acc);
        }
        int col = ct * 32 + cl;
        if (col < 784) {
            float bias = B7[n * 784 + col];
#pragma unroll
            for (int r2 = 0; r2 < 16; ++r2) rowsum[r2] += fast_tanh(acc[r2] + bias);
        }
    }

    // reduce across the 32 column-lanes (stays within each half)
#pragma unroll
    for (int r2 = 0; r2 < 16; ++r2) {
        float s = rowsum[r2];
        s += __shfl_xor(s, 1);  s += __shfl_xor(s, 2);  s += __shfl_xor(s, 4);
        s += __shfl_xor(s, 8);  s += __shfl_xor(s, 16);
        rowsum[r2] = s;
    }

    float* Ps = HsB;            // 256 floats, HsB is dead now
    Ps[t] = 0.f;
    __syncthreads();
    if (cl == 0) {
#pragma unroll
        for (int r2 = 0; r2 < 16; ++r2) {
            int row = rtl * 32 + (r2 & 3) + 8 * (r2 >> 2) + 4 * hf;
            Ps[w * 64 + row] = rowsum[r2];
        }
    }
    __syncthreads();
    if (t < 64) {
        float s = Ps[t] + Ps[64 + t] + Ps[128 + t] + Ps[192 + t];
        out[(size_t)(blockIdx.y * 64 + t) * 10 + n] = s;
    }
}

// ---------------- fp32 fallback (round-1 kernel) if ws too small -------------
__global__ __launch_bounds__(256)
void fused_ae_fp32_kernel(const float* __restrict__ x,
                          const float* __restrict__ W0, const float* __restrict__ B0,
                          const float* __restrict__ W1, const float* __restrict__ B1,
                          const float* __restrict__ W2, const float* __restrict__ B2,
                          const float* __restrict__ W3, const float* __restrict__ B3,
                          const float* __restrict__ W4, const float* __restrict__ B4,
                          const float* __restrict__ W5, const float* __restrict__ B5,
                          const float* __restrict__ W6, const float* __restrict__ B6,
                          const float* __restrict__ W7, const float* __restrict__ B7,
                          float* __restrict__ out) {
    __shared__ float HsA[128 * 65];
    __shared__ float HsB[64 * 65];
    const int t    = threadIdx.x;
    const int lane = t & 63;
    const int w    = __builtin_amdgcn_readfirstlane(t >> 6);
    const int n    = blockIdx.x;
    const int rowbase = blockIdx.y * 64;

    float acc0[32];
#pragma unroll
    for (int j = 0; j < 32; ++j) acc0[j] = 0.f;
    float* As = HsB;
    const int r   = t >> 2;
    const int kk4 = (t & 3) * 4;
    const float* xrow = x + (size_t)(rowbase + r) * 784;
    for (int kc = 0; kc < 49; ++kc) {
        float4 xv = *(const float4*)(xrow + kc * 16 + kk4);
        As[(kk4 + 0) * 65 + r] = xv.x;
        As[(kk4 + 1) * 65 + r] = xv.y;
        As[(kk4 + 2) * 65 + r] = xv.z;
        As[(kk4 + 3) * 65 + r] = xv.w;
        __syncthreads();
        const float* W0base = W0 + ((size_t)n * 784 + (size_t)kc * 16) * 128 + w * 32;
#pragma unroll
        for (int k = 0; k < 16; ++k) {
            float a = As[k * 65 + lane];
            const float* Wk = W0base + k * 128;
#pragma unroll
            for (int j = 0; j < 32; ++j) acc0[j] = fmaf(a, Wk[j], acc0[j]);
        }
        __syncthreads();
    }
    {
        const float* bb = B0 + n * 128 + w * 32;
#pragma unroll
        for (int j = 0; j < 32; ++j)
            HsA[(w * 32 + j) * 65 + lane] = fmaxf(acc0[j] + bb[j], 0.f);
    }
    __syncthreads();

    midlayer<128, 64, 16, true >(W1, B1, HsA, HsB, n, w, lane);
    midlayer< 64, 12,  3, true >(W2, B2, HsB, HsA, n, w, lane);
    midlayer< 12,  3,  1, false>(W3, B3, HsA, HsB, n, w, lane);
    midlayer<  3, 12,  3, true >(W4, B4, HsB, HsA, n, w, lane);
    midlayer< 12, 64, 16, true >(W5, B5, HsA, HsB, n, w, lane);
    midlayer< 64,128, 32, true >(W6, B6, HsB, HsA, n, w, lane);

    float lane_sum = 0.f;
    const int j0w = w * 196;
    for (int c = 0; c < 7; ++c) {
        const int j0 = j0w + c * 28;
        float acc[28];
        const float* bb = B7 + n * 784 + j0;
#pragma unroll
        for (int j = 0; j < 28; ++j) acc[j] = bb[j];
        for (int k = 0; k < 128; ++k) {
            float a = HsA[k * 65 + lane];
            const float* Wk = W7 + ((size_t)n * 128 + k) * 784 + j0;
#pragma unroll
            for (int j = 0; j < 28; ++j) acc[j] = fmaf(a, Wk[j], acc[j]);
        }
#pragma unroll
        for (int j = 0; j < 28; ++j) lane_sum += fast_tanh(acc[j]);
    }
    float* partial = HsB;
    partial[w * 64 + lane] = lane_sum;
    __syncthreads();
    if (t < 64) {
        float s = partial[t] + partial[64 + t] + partial[128 + t] + partial[192 + t];
        out[(size_t)(rowbase + t) * 10 + n] = s;
    }
}

extern "C" void kernel_launch(void* const* d_in, const int* in_sizes, int n_in,
                              void* d_out, int out_size, void* d_ws, size_t ws_size,
                              hipStream_t stream) {
    (void)in_sizes; (void)n_in; (void)out_size;
    const float* x  = (const float*)d_in[0];
    const float* W0 = (const float*)d_in[1];  const float* B0 = (const float*)d_in[2];
    const float* W1 = (const float*)d_in[3];  const float* B1 = (const float*)d_in[4];
    const float* W2 = (const float*)d_in[5];  const float* B2 = (const float*)d_in[6];
    const float* W3 = (const float*)d_in[7];  const float* B3 = (const float*)d_in[8];
    const float* W4 = (const float*)d_in[9];  const float* B4 = (const float*)d_in[10];
    const float* W5 = (const float*)d_in[11]; const float* B5 = (const float*)d_in[12];
    const float* W6 = (const float*)d_in[13]; const float* B6 = (const float*)d_in[14];
    const float* W7 = (const float*)d_in[15]; const float* B7 = (const float*)d_in[16];
    float* out = (float*)d_out;

    if (ws_size >= TOTAL_WS) {
        unsigned short* ws_u16 = (unsigned short*)d_ws;
        hipLaunchKernelGGL(pack_x_kernel,  dim3(3136), dim3(256), 0, stream, x,  ws_u16);
        hipLaunchKernelGGL(pack_w0_kernel, dim3(490),  dim3(256), 0, stream, W0, ws_u16 + W0PACK_OFF / 2);
        hipLaunchKernelGGL(pack_w7_kernel, dim3(500),  dim3(256), 0, stream, W7, ws_u16 + W7PACK_OFF / 2);
        hipLaunchKernelGGL(fused_ae_mfma_kernel, dim3(NNETS, BATCH / 64), dim3(256), 0, stream,
                           x, B0, W1, B1, W2, B2, W3, B3,
                           W4, B4, W5, B5, W6, B6, B7, ws_u16, out);
    } else {
        hipLaunchKernelGGL(fused_ae_fp32_kernel, dim3(NNETS, BATCH / 64), dim3(256), 0, stream,
                           x, W0, B0, W1, B1, W2, B2, W3, B3,
                           W4, B4, W5, B5, W6, B6, W7, B7, out);
    }
}

// Round 4
// 287.586 us; speedup vs baseline: 2.7651x; 1.3542x over previous
//
#include <hip/hip_runtime.h>

#define NNETS 10
#define BATCH 8192

typedef __attribute__((ext_vector_type(8)))  short  short8;
typedef __attribute__((ext_vector_type(16))) float  f32x16;

// ---------------- workspace layout (bytes) ----------------
// xpack : [rt(256)][kc(49)][hl(2)][lane(64)][j(8)] bf16
// w0pack: [n(10)][kc(49)][ct(4)][hl(2)][lane(64)][j(8)]
// w7pack: [n(10)][kc(8)][ct(25)][hl(2)][lane(64)][j(8)]
// w1pack: [n(10)][kc(8)][ct(2)][hl(2)][lane(64)][j(8)]
// w6pack: [n(10)][kc(4)][ct(4)][hl(2)][lane(64)][j(8)]
#define XPACK_BYTES  (256UL*49*2*64*8*2)
#define W0PACK_OFF   (XPACK_BYTES)
#define W0PACK_BYTES (10UL*49*4*2*64*8*2)
#define W7PACK_OFF   (W0PACK_OFF + W0PACK_BYTES)
#define W7PACK_BYTES (10UL*8*25*2*64*8*2)
#define W1PACK_OFF   (W7PACK_OFF + W7PACK_BYTES)
#define W1PACK_BYTES (10UL*8*2*2*64*8*2)
#define W6PACK_OFF   (W1PACK_OFF + W1PACK_BYTES)
#define W6PACK_BYTES (10UL*4*4*2*64*8*2)
#define TOTAL_WS     (W6PACK_OFF + W6PACK_BYTES)

// ---------------- helpers ----------------
__device__ __forceinline__ float fast_tanh(float x) {
    float e = __expf(2.f * x);
    return 1.f - 2.f / (1.f + e);
}
__device__ __forceinline__ unsigned short bf16_rne(float v) {
    unsigned u = __float_as_uint(v);
    unsigned r = (u + 0x7FFFu + ((u >> 16) & 1u)) >> 16;
    return (unsigned short)r;
}
__device__ __forceinline__ float bf16_to_f(unsigned short h) {
    return __uint_as_float(((unsigned)h) << 16);
}
// split v into bf16 hi/lo, packed (hi in low 16, lo in high 16)
__device__ __forceinline__ unsigned split_pack(float v) {
    unsigned short h = bf16_rne(v);
    unsigned short l = bf16_rne(v - bf16_to_f(h));
    return (unsigned)h | ((unsigned)l << 16);
}

// ---------------- pack kernels ----------------
// x: coalesced reads (consecutive tid -> consecutive 32B of same row)
__global__ __launch_bounds__(256)
void pack_x_kernel(const float* __restrict__ x, unsigned short* __restrict__ xp) {
    int tid = blockIdx.x * 256 + threadIdx.x;           // 8192*98 = 802816
    if (tid >= 8192 * 98) return;
    int row = tid / 98;
    int kbi = tid - row * 98;           // 8-float chunk index within row
    int kc  = kbi >> 1;
    int hf  = kbi & 1;
    const float* src = x + (size_t)row * 784 + kbi * 8;
    short8 H, L;
#pragma unroll
    for (int j = 0; j < 8; ++j) {
        float v = src[j];
        unsigned short h = bf16_rne(v);
        H[j] = (short)h;
        L[j] = (short)bf16_rne(v - bf16_to_f(h));
    }
    int rt = row >> 5;
    int lane_dst = hf * 32 + (row & 31);
    short8* dst = reinterpret_cast<short8*>(xp + (size_t)(rt * 49 + kc) * 1024) + lane_dst;
    dst[0]  = H;
    dst[64] = L;
}

__global__ __launch_bounds__(256)
void pack_w0_kernel(const float* __restrict__ W0, unsigned short* __restrict__ wp) {
    int tid = blockIdx.x * 256 + threadIdx.x;           // 10*49*4*64 = 125440
    if (tid >= 10 * 49 * 4 * 64) return;
    int lane = tid & 63; int t2 = tid >> 6;
    int ct = t2 % 4;  t2 /= 4;
    int kc = t2 % 49; int n = t2 / 49;
    int col = ct * 32 + (lane & 31);
    int kb  = kc * 16 + 8 * (lane >> 5);
    short8 H, L;
#pragma unroll
    for (int j = 0; j < 8; ++j) {
        float v = W0[((size_t)n * 784 + kb + j) * 128 + col];
        unsigned short h = bf16_rne(v);
        H[j] = (short)h;
        L[j] = (short)bf16_rne(v - bf16_to_f(h));
    }
    short8* dst = reinterpret_cast<short8*>(wp + (size_t)((n * 49 + kc) * 4 + ct) * 1024) + lane;
    dst[0]  = H;
    dst[64] = L;
}

__global__ __launch_bounds__(256)
void pack_w7_kernel(const float* __restrict__ W7, unsigned short* __restrict__ wp) {
    int tid = blockIdx.x * 256 + threadIdx.x;           // 10*8*25*64 = 128000
    if (tid >= 10 * 8 * 25 * 64) return;
    int lane = tid & 63; int t2 = tid >> 6;
    int ct = t2 % 25; t2 /= 25;
    int kc = t2 % 8;  int n = t2 / 8;
    int col = ct * 32 + (lane & 31);
    int kb  = kc * 16 + 8 * (lane >> 5);
    short8 H, L;
#pragma unroll
    for (int j = 0; j < 8; ++j) {
        float v = (col < 784) ? W7[((size_t)n * 128 + kb + j) * 784 + col] : 0.f;
        unsigned short h = bf16_rne(v);
        H[j] = (short)h;
        L[j] = (short)bf16_rne(v - bf16_to_f(h));
    }
    short8* dst = reinterpret_cast<short8*>(wp + (size_t)((n * 8 + kc) * 25 + ct) * 1024) + lane;
    dst[0]  = H;
    dst[64] = L;
}

__global__ __launch_bounds__(256)
void pack_w1_kernel(const float* __restrict__ W1, unsigned short* __restrict__ wp) {
    int tid = blockIdx.x * 256 + threadIdx.x;           // 10*8*2*64 = 10240
    if (tid >= 10 * 8 * 2 * 64) return;
    int lane = tid & 63; int t2 = tid >> 6;
    int ct = t2 % 2; t2 /= 2;
    int kc = t2 % 8; int n = t2 / 8;
    int col = ct * 32 + (lane & 31);
    int kb  = kc * 16 + 8 * (lane >> 5);
    short8 H, L;
#pragma unroll
    for (int j = 0; j < 8; ++j) {
        float v = W1[((size_t)n * 128 + kb + j) * 64 + col];
        unsigned short h = bf16_rne(v);
        H[j] = (short)h;
        L[j] = (short)bf16_rne(v - bf16_to_f(h));
    }
    short8* dst = reinterpret_cast<short8*>(wp + (size_t)((n * 8 + kc) * 2 + ct) * 1024) + lane;
    dst[0]  = H;
    dst[64] = L;
}

__global__ __launch_bounds__(256)
void pack_w6_kernel(const float* __restrict__ W6, unsigned short* __restrict__ wp) {
    int tid = blockIdx.x * 256 + threadIdx.x;           // 10*4*4*64 = 10240
    if (tid >= 10 * 4 * 4 * 64) return;
    int lane = tid & 63; int t2 = tid >> 6;
    int ct = t2 % 4; t2 /= 4;
    int kc = t2 % 4; int n = t2 / 4;
    int col = ct * 32 + (lane & 31);
    int kb  = kc * 16 + 8 * (lane >> 5);
    short8 H, L;
#pragma unroll
    for (int j = 0; j < 8; ++j) {
        float v = W6[((size_t)n * 64 + kb + j) * 128 + col];
        unsigned short h = bf16_rne(v);
        H[j] = (short)h;
        L[j] = (short)bf16_rne(v - bf16_to_f(h));
    }
    short8* dst = reinterpret_cast<short8*>(wp + (size_t)((n * 4 + kc) * 4 + ct) * 1024) + lane;
    dst[0]  = H;
    dst[64] = L;
}

// ---------------- small mid layers (fp32 VALU) ----------------
template<int ID, int OD, int NO, bool RELU>
__device__ __forceinline__ void midlayer(const float* __restrict__ W,
                                         const float* __restrict__ bias,
                                         const float* bufIn, float* bufOut,
                                         int n, int w, int lane) {
    const int o0 = w * NO;
    if (o0 < OD) {
        float acc[NO];
#pragma unroll
        for (int j = 0; j < NO; ++j) acc[j] = bias[n * OD + o0 + j];
        for (int k = 0; k < ID; ++k) {
            float a = bufIn[k * 65 + lane];
            const float* Wk = W + ((size_t)n * ID + k) * OD + o0;
#pragma unroll
            for (int j = 0; j < NO; ++j) acc[j] = fmaf(a, Wk[j], acc[j]);
        }
#pragma unroll
        for (int j = 0; j < NO; ++j) {
            float v = acc[j];
            if (RELU) v = fmaxf(v, 0.f);
            bufOut[(o0 + j) * 65 + lane] = v;
        }
    }
    __syncthreads();
}

#define MFMA32(A, B, C) __builtin_amdgcn_mfma_f32_32x32x16_bf16(A, B, C, 0, 0, 0)

// ---------------- main fused kernel ----------------
__global__ __launch_bounds__(256)
void fused_ae_mfma_kernel(const float* __restrict__ B0,
                          const float* __restrict__ B1,
                          const float* __restrict__ W2, const float* __restrict__ B2,
                          const float* __restrict__ W3, const float* __restrict__ B3,
                          const float* __restrict__ W4, const float* __restrict__ B4,
                          const float* __restrict__ W5, const float* __restrict__ B5,
                          const float* __restrict__ B6,
                          const float* __restrict__ B7,
                          const unsigned short* __restrict__ ws_u16,
                          float* __restrict__ out) {
    __shared__ float HsA[128 * 65];   // 33.3 KB: h0(pk)/h2/h4/h6(pk)
    __shared__ float HsB[64 * 65];    // 16.6 KB: h1/h3/h5/partials
    unsigned* HsAu = reinterpret_cast<unsigned*>(HsA);

    const int t    = threadIdx.x;
    const int lane = t & 63;
    const int w    = __builtin_amdgcn_readfirstlane(t >> 6);  // wave 0..3
    const int n    = blockIdx.x;
    const int cl   = lane & 31;
    const int hf   = lane >> 5;
    const int rtl  = w >> 1;          // local 32-row tile 0/1
    const int ct0  = (w & 1) * 2;     // L0/L6 col-tile pair

    const short8* xp8  = reinterpret_cast<const short8*>(ws_u16);
    const short8* w0p8 = reinterpret_cast<const short8*>(ws_u16 + W0PACK_OFF / 2);
    const short8* w7p8 = reinterpret_cast<const short8*>(ws_u16 + W7PACK_OFF / 2);
    const short8* w1p8 = reinterpret_cast<const short8*>(ws_u16 + W1PACK_OFF / 2);
    const short8* w6p8 = reinterpret_cast<const short8*>(ws_u16 + W6PACK_OFF / 2);

    // ================= Layer 0: x @ W0 -> h0 (packed u32), relu =================
    const int rt = blockIdx.y * 2 + rtl;
    f32x16 acc0, acc1;
#pragma unroll
    for (int i = 0; i < 16; ++i) { acc0[i] = 0.f; acc1[i] = 0.f; }

    const short8* xA = xp8 + (size_t)rt * 49 * 128 + lane;
    const short8* wB = w0p8 + ((size_t)n * 49 * 4 + ct0) * 128 + lane;

    short8 Ah = xA[0], Al = xA[64];
    short8 Bh0 = wB[0], Bl0 = wB[64], Bh1 = wB[128], Bl1 = wB[192];
    for (int kc = 0; kc < 49; ++kc) {
        short8 nAh, nAl, nBh0, nBl0, nBh1, nBl1;
        if (kc < 48) {
            const short8* xn = xA + (size_t)(kc + 1) * 128;
            const short8* wn = wB + (size_t)(kc + 1) * 512;
            nAh = xn[0]; nAl = xn[64];
            nBh0 = wn[0]; nBl0 = wn[64]; nBh1 = wn[128]; nBl1 = wn[192];
        }
        acc0 = MFMA32(Ah, Bh0, acc0);
        acc0 = MFMA32(Ah, Bl0, acc0);
        acc0 = MFMA32(Al, Bh0, acc0);
        acc1 = MFMA32(Ah, Bh1, acc1);
        acc1 = MFMA32(Ah, Bl1, acc1);
        acc1 = MFMA32(Al, Bh1, acc1);
        if (kc < 48) { Ah = nAh; Al = nAl; Bh0 = nBh0; Bl0 = nBl0; Bh1 = nBh1; Bl1 = nBl1; }
    }
    {
        float b0a = B0[n * 128 + ct0 * 32 + cl];
        float b0b = B0[n * 128 + (ct0 + 1) * 32 + cl];
#pragma unroll
        for (int r2 = 0; r2 < 16; ++r2) {
            int row = rtl * 32 + (r2 & 3) + 8 * (r2 >> 2) + 4 * hf;
            HsAu[(ct0 * 32 + cl) * 65 + row]       = split_pack(fmaxf(acc0[r2] + b0a, 0.f));
            HsAu[((ct0 + 1) * 32 + cl) * 65 + row] = split_pack(fmaxf(acc1[r2] + b0b, 0.f));
        }
    }
    __syncthreads();

    // ================= Layer 1: h0 @ W1 -> h1[64][65] fp32, relu (MFMA) ==========
    {
        const int ctl = w & 1;
        short8 a_hi[8], a_lo[8];
        const int r32 = rtl * 32 + cl;
#pragma unroll
        for (int kc = 0; kc < 8; ++kc) {
            int kb = kc * 16 + 8 * hf;
            short8 H, L;
#pragma unroll
            for (int j = 0; j < 8; ++j) {
                unsigned u = HsAu[(kb + j) * 65 + r32];
                H[j] = (short)(u & 0xFFFFu);
                L[j] = (short)(u >> 16);
            }
            a_hi[kc] = H; a_lo[kc] = L;
        }
        f32x16 acc;
#pragma unroll
        for (int i = 0; i < 16; ++i) acc[i] = 0.f;
        const short8* wb = w1p8 + ((size_t)n * 8 * 2 + ctl) * 128 + lane;
#pragma unroll
        for (int kc = 0; kc < 8; ++kc) {
            const short8* bp = wb + (size_t)kc * 256;
            short8 Bh = bp[0], Bl = bp[64];
            acc = MFMA32(a_hi[kc], Bh, acc);
            acc = MFMA32(a_hi[kc], Bl, acc);
            acc = MFMA32(a_lo[kc], Bh, acc);
        }
        __syncthreads();   // all h0 reads complete before h1 write below
        float bias = B1[n * 64 + ctl * 32 + cl];
#pragma unroll
        for (int r2 = 0; r2 < 16; ++r2) {
            int row = rtl * 32 + (r2 & 3) + 8 * (r2 >> 2) + 4 * hf;
            HsB[(ctl * 32 + cl) * 65 + row] = fmaxf(acc[r2] + bias, 0.f);
        }
    }
    __syncthreads();

    // ================= Layers 2..5 (fp32 VALU, LDS ping-pong) ====================
    midlayer< 64, 12,  3, true >(W2, B2, HsB, HsA, n, w, lane);  // h1(B)->h2(A)
    midlayer< 12,  3,  1, false>(W3, B3, HsA, HsB, n, w, lane);  // h2(A)->h3(B)
    midlayer<  3, 12,  3, true >(W4, B4, HsB, HsA, n, w, lane);  // h3(B)->h4(A)
    midlayer< 12, 64, 16, true >(W5, B5, HsA, HsB, n, w, lane);  // h4(A)->h5(B)

    // ================= Layer 6: h5 @ W6 -> h6 (packed u32), relu (MFMA) ==========
    {
        short8 a_hi[4], a_lo[4];
        const int r32 = rtl * 32 + cl;
#pragma unroll
        for (int kc = 0; kc < 4; ++kc) {
            int kb = kc * 16 + 8 * hf;
            short8 H, L;
#pragma unroll
            for (int j = 0; j < 8; ++j) {
                float v = HsB[(kb + j) * 65 + r32];
                unsigned short h = bf16_rne(v);
                H[j] = (short)h;
                L[j] = (short)bf16_rne(v - bf16_to_f(h));
            }
            a_hi[kc] = H; a_lo[kc] = L;
        }
        f32x16 acc0, acc1;
#pragma unroll
        for (int i = 0; i < 16; ++i) { acc0[i] = 0.f; acc1[i] = 0.f; }
        const short8* wb = w6p8 + ((size_t)n * 4 * 4 + ct0) * 128 + lane;
#pragma unroll
        for (int kc = 0; kc < 4; ++kc) {
            const short8* bp = wb + (size_t)kc * 512;
            short8 Bh0 = bp[0],   Bl0 = bp[64];
            short8 Bh1 = bp[128], Bl1 = bp[192];
            acc0 = MFMA32(a_hi[kc], Bh0, acc0);
            acc0 = MFMA32(a_hi[kc], Bl0, acc0);
            acc0 = MFMA32(a_lo[kc], Bh0, acc0);
            acc1 = MFMA32(a_hi[kc], Bh1, acc1);
            acc1 = MFMA32(a_hi[kc], Bl1, acc1);
            acc1 = MFMA32(a_lo[kc], Bh1, acc1);
        }
        __syncthreads();   // h5 reads done before HsA h6-write (HsA holds h4; dead)
        float b6a = B6[n * 128 + ct0 * 32 + cl];
        float b6b = B6[n * 128 + (ct0 + 1) * 32 + cl];
#pragma unroll
        for (int r2 = 0; r2 < 16; ++r2) {
            int row = rtl * 32 + (r2 & 3) + 8 * (r2 >> 2) + 4 * hf;
            HsAu[(ct0 * 32 + cl) * 65 + row]       = split_pack(fmaxf(acc0[r2] + b6a, 0.f));
            HsAu[((ct0 + 1) * 32 + cl) * 65 + row] = split_pack(fmaxf(acc1[r2] + b6b, 0.f));
        }
    }
    __syncthreads();

    // ================= Layer 7: h6 @ W7, tanh, row-sum ===========================
    short8 a_hi[8], a_lo[8];
    {
        const int r32 = rtl * 32 + cl;
#pragma unroll
        for (int kc = 0; kc < 8; ++kc) {
            int kb = kc * 16 + 8 * hf;
            short8 H, L;
#pragma unroll
            for (int j = 0; j < 8; ++j) {
                unsigned u = HsAu[(kb + j) * 65 + r32];
                H[j] = (short)(u & 0xFFFFu);
                L[j] = (short)(u >> 16);
            }
            a_hi[kc] = H; a_lo[kc] = L;
        }
    }

    float rowsum[16];
#pragma unroll
    for (int i = 0; i < 16; ++i) rowsum[i] = 0.f;

    const short8* w7b = w7p8 + (size_t)n * 8 * 25 * 128 + lane;
    const int ctS = (w & 1) ? 13 : 0;
    const int ctE = (w & 1) ? 25 : 13;
    for (int ct = ctS; ct < ctE; ++ct) {
        f32x16 acc;
#pragma unroll
        for (int i = 0; i < 16; ++i) acc[i] = 0.f;
#pragma unroll
        for (int kc = 0; kc < 8; ++kc) {
            const short8* bp = w7b + (size_t)(kc * 25 + ct) * 128;
            short8 Bh = bp[0], Bl = bp[64];
            acc = MFMA32(a_hi[kc], Bh, acc);
            acc = MFMA32(a_hi[kc], Bl, acc);
            acc = MFMA32(a_lo[kc], Bh, acc);
        }
        int col = ct * 32 + cl;
        if (col < 784) {
            float bias = B7[n * 784 + col];
#pragma unroll
            for (int r2 = 0; r2 < 16; ++r2) rowsum[r2] += fast_tanh(acc[r2] + bias);
        }
    }

#pragma unroll
    for (int r2 = 0; r2 < 16; ++r2) {
        float s = rowsum[r2];
        s += __shfl_xor(s, 1);  s += __shfl_xor(s, 2);  s += __shfl_xor(s, 4);
        s += __shfl_xor(s, 8);  s += __shfl_xor(s, 16);
        rowsum[r2] = s;
    }

    float* Ps = HsB;   // HsB (h5) dead; h5 reads all completed before L6's barrier
    Ps[t] = 0.f;       // REQUIRED: each wave writes only 32 of its 64 slots below
    __syncthreads();
    if (cl == 0) {
#pragma unroll
        for (int r2 = 0; r2 < 16; ++r2) {
            int row = rtl * 32 + (r2 & 3) + 8 * (r2 >> 2) + 4 * hf;
            Ps[w * 64 + row] = rowsum[r2];
        }
    }
    __syncthreads();
    if (t < 64) {
        float s = Ps[t] + Ps[64 + t] + Ps[128 + t] + Ps[192 + t];
        out[(size_t)(blockIdx.y * 64 + t) * 10 + n] = s;
    }
}

// ---------------- fp32 fallback if ws too small ----------------
__global__ __launch_bounds__(256)
void fused_ae_fp32_kernel(const float* __restrict__ x,
                          const float* __restrict__ W0, const float* __restrict__ B0,
                          const float* __restrict__ W1, const float* __restrict__ B1,
                          const float* __restrict__ W2, const float* __restrict__ B2,
                          const float* __restrict__ W3, const float* __restrict__ B3,
                          const float* __restrict__ W4, const float* __restrict__ B4,
                          const float* __restrict__ W5, const float* __restrict__ B5,
                          const float* __restrict__ W6, const float* __restrict__ B6,
                          const float* __restrict__ W7, const float* __restrict__ B7,
                          float* __restrict__ out) {
    __shared__ float HsA[128 * 65];
    __shared__ float HsB[64 * 65];
    const int t    = threadIdx.x;
    const int lane = t & 63;
    const int w    = __builtin_amdgcn_readfirstlane(t >> 6);
    const int n    = blockIdx.x;
    const int rowbase = blockIdx.y * 64;

    float acc0[32];
#pragma unroll
    for (int j = 0; j < 32; ++j) acc0[j] = 0.f;
    float* As = HsB;
    const int r   = t >> 2;
    const int kk4 = (t & 3) * 4;
    const float* xrow = x + (size_t)(rowbase + r) * 784;
    for (int kc = 0; kc < 49; ++kc) {
        float4 xv = *(const float4*)(xrow + kc * 16 + kk4);
        As[(kk4 + 0) * 65 + r] = xv.x;
        As[(kk4 + 1) * 65 + r] = xv.y;
        As[(kk4 + 2) * 65 + r] = xv.z;
        As[(kk4 + 3) * 65 + r] = xv.w;
        __syncthreads();
        const float* W0base = W0 + ((size_t)n * 784 + (size_t)kc * 16) * 128 + w * 32;
#pragma unroll
        for (int k = 0; k < 16; ++k) {
            float a = As[k * 65 + lane];
            const float* Wk = W0base + k * 128;
#pragma unroll
            for (int j = 0; j < 32; ++j) acc0[j] = fmaf(a, Wk[j], acc0[j]);
        }
        __syncthreads();
    }
    {
        const float* bb = B0 + n * 128 + w * 32;
#pragma unroll
        for (int j = 0; j < 32; ++j)
            HsA[(w * 32 + j) * 65 + lane] = fmaxf(acc0[j] + bb[j], 0.f);
    }
    __syncthreads();

    midlayer<128, 64, 16, true >(W1, B1, HsA, HsB, n, w, lane);
    midlayer< 64, 12,  3, true >(W2, B2, HsB, HsA, n, w, lane);
    midlayer< 12,  3,  1, false>(W3, B3, HsA, HsB, n, w, lane);
    midlayer<  3, 12,  3, true >(W4, B4, HsB, HsA, n, w, lane);
    midlayer< 12, 64, 16, true >(W5, B5, HsA, HsB, n, w, lane);
    midlayer< 64,128, 32, true >(W6, B6, HsB, HsA, n, w, lane);

    float lane_sum = 0.f;
    const int j0w = w * 196;
    for (int c = 0; c < 7; ++c) {
        const int j0 = j0w + c * 28;
        float acc[28];
        const float* bb = B7 + n * 784 + j0;
#pragma unroll
        for (int j = 0; j < 28; ++j) acc[j] = bb[j];
        for (int k = 0; k < 128; ++k) {
            float a = HsA[k * 65 + lane];
            const float* Wk = W7 + ((size_t)n * 128 + k) * 784 + j0;
#pragma unroll
            for (int j = 0; j < 28; ++j) acc[j] = fmaf(a, Wk[j], acc[j]);
        }
#pragma unroll
        for (int j = 0; j < 28; ++j) lane_sum += fast_tanh(acc[j]);
    }
    float* partial = HsB;
    partial[w * 64 + lane] = lane_sum;
    __syncthreads();
    if (t < 64) {
        float s = partial[t] + partial[64 + t] + partial[128 + t] + partial[192 + t];
        out[(size_t)(rowbase + t) * 10 + n] = s;
    }
}

extern "C" void kernel_launch(void* const* d_in, const int* in_sizes, int n_in,
                              void* d_out, int out_size, void* d_ws, size_t ws_size,
                              hipStream_t stream) {
    (void)in_sizes; (void)n_in; (void)out_size;
    const float* x  = (const float*)d_in[0];
    const float* W0 = (const float*)d_in[1];  const float* B0 = (const float*)d_in[2];
    const float* W1 = (const float*)d_in[3];  const float* B1 = (const float*)d_in[4];
    const float* W2 = (const float*)d_in[5];  const float* B2 = (const float*)d_in[6];
    const float* W3 = (const float*)d_in[7];  const float* B3 = (const float*)d_in[8];
    const float* W4 = (const float*)d_in[9];  const float* B4 = (const float*)d_in[10];
    const float* W5 = (const float*)d_in[11]; const float* B5 = (const float*)d_in[12];
    const float* W6 = (const float*)d_in[13]; const float* B6 = (const float*)d_in[14];
    const float* W7 = (const float*)d_in[15]; const float* B7 = (const float*)d_in[16];
    float* out = (float*)d_out;

    if (ws_size >= TOTAL_WS) {
        unsigned short* ws_u16 = (unsigned short*)d_ws;
        hipLaunchKernelGGL(pack_x_kernel,  dim3(3136), dim3(256), 0, stream, x,  ws_u16);
        hipLaunchKernelGGL(pack_w0_kernel, dim3(490),  dim3(256), 0, stream, W0, ws_u16 + W0PACK_OFF / 2);
        hipLaunchKernelGGL(pack_w7_kernel, dim3(500),  dim3(256), 0, stream, W7, ws_u16 + W7PACK_OFF / 2);
        hipLaunchKernelGGL(pack_w1_kernel, dim3(40),   dim3(256), 0, stream, W1, ws_u16 + W1PACK_OFF / 2);
        hipLaunchKernelGGL(pack_w6_kernel, dim3(40),   dim3(256), 0, stream, W6, ws_u16 + W6PACK_OFF / 2);
        hipLaunchKernelGGL(fused_ae_mfma_kernel, dim3(NNETS, BATCH / 64), dim3(256), 0, stream,
                           B0, B1, W2, B2, W3, B3, W4, B4, W5, B5, B6, B7, ws_u16, out);
    } else {
        hipLaunchKernelGGL(fused_ae_fp32_kernel, dim3(NNETS, BATCH / 64), dim3(256), 0, stream,
                           x, W0, B0, W1, B1, W2, B2, W3, B3,
                           W4, B4, W5, B5, W6, B6, W7, B7, out);
    }
}